// Round 17
// baseline (59.135 us; speedup 1.0000x reference)
//
#include <hip/hip_runtime.h>
#include <math.h>

#define H 256
#define W 256
#define HW (H * W)
#define CH 24
#define NK 63
#define T1S 24          // t1 per-pixel stride in shorts (48 B = 12 dwords, 2-way floor)
#define TBS 24          // tbt per-pixel stride in shorts
#define KSTEPS 25       // K = 25 taps * 32 (24 ch + 8 zero-pad)
#define T3S 26          // t3 per-pixel stride in floats

typedef short v8s __attribute__((ext_vector_type(8)));
typedef short v4s __attribute__((ext_vector_type(4)));
typedef float v4f __attribute__((ext_vector_type(4)));

// ---------------- analytic RBF ------------------------------------------------
struct RbfCtx {
    float m0, istep, c2a, ahalf, dfac;
    float G1, G2, G3, G4;
};
__device__ __forceinline__ RbfCtx make_ctx(const float* __restrict__ mean) {
    RbfCtx c;
    c.m0 = mean[0];
    float m62 = mean[NK - 1];
    float step = (m62 - c.m0) * (1.f / (float)(NK - 1));
    c.istep = (float)(NK - 1) / (m62 - c.m0);
    float a = step * step * (1.f / 200.f);
    c.c2a = 2.f * a;
    c.ahalf = a;
    c.dfac = -step * 0.01f;
    c.G1 = __expf(-a);
    c.G2 = __expf(-4.f * a);
    c.G3 = __expf(-9.f * a);
    c.G4 = __expf(-16.f * a);
    return c;
}

template<bool DER>
__device__ __forceinline__ float rbf_eval(float v, const float* __restrict__ wrow,
                                          const RbfCtx& c) {
    float t = (v - c.m0) * c.istep;
    float kcf = floorf(t + 0.5f);
    kcf = fminf(fmaxf(kcf, 4.f), (float)(NK - 5));
    int kc = (int)kcf;
    float f = t - kcf;
    f = fminf(fmaxf(f, -12.f), 12.f);
    float g  = c.c2a * f;
    float E1 = __expf(g), R1 = __expf(-g);
    float E2 = E1 * E1, R2 = R1 * R1;
    float gpm4 = c.G4 * R2 * R2, gpm3 = c.G3 * R2 * R1, gpm2 = c.G2 * R2, gpm1 = c.G1 * R1;
    float gpp1 = c.G1 * E1, gpp2 = c.G2 * E2, gpp3 = c.G3 * E2 * E1, gpp4 = c.G4 * E2 * E2;
    const float* p = wrow + (kc - 4);
    float m_m4 = p[0] * gpm4, m_m3 = p[1] * gpm3, m_m2 = p[2] * gpm2, m_m1 = p[3] * gpm1;
    float m_0  = p[4];
    float m_p1 = p[5] * gpp1, m_p2 = p[6] * gpp2, m_p3 = p[7] * gpp3, m_p4 = p[8] * gpp4;
    float S0 = ((m_m4 + m_m3) + (m_m2 + m_m1)) + m_0 + ((m_p1 + m_p2) + (m_p3 + m_p4));
    float base = __expf(-c.ahalf * f * f);
    if (!DER) return base * S0;
    float S1 = 0.f;
    S1 = fmaf(m_m4, -4.f, S1); S1 = fmaf(m_m3, -3.f, S1);
    S1 = fmaf(m_m2, -2.f, S1); S1 = fmaf(m_m1, -1.f, S1);
    S1 = fmaf(m_p1,  1.f, S1); S1 = fmaf(m_p2,  2.f, S1);
    S1 = fmaf(m_p3,  3.f, S1); S1 = fmaf(m_p4,  4.f, S1);
    return c.dfac * base * fmaf(f, S0, -S1);
}

__device__ __forceinline__ short f2bf(float v) {
    unsigned u = __float_as_uint(v);
    u += 0x7fff + ((u >> 16) & 1);
    return (short)(u >> 16);
}

// ---------------- prep: norms + A-fragment pack --------------------------------
// abuf: [mode 2][mtile 2][kstep 25][lane 64] v8s. k = tap*32 + c (c<24, pad=0).
__global__ void k_prep(const float* __restrict__ f0, const float* __restrict__ f1,
                       float* __restrict__ f0n, float* __restrict__ f0t,
                       v8s* __restrict__ abuf) {
    __shared__ float red[256];
    int tid = threadIdx.x;
    float s1 = 0.f;
    for (int i = tid; i < 14400; i += 256) s1 += f1[i] * f1[i];
    red[tid] = s1; __syncthreads();
    for (int off = 128; off; off >>= 1) { if (tid < off) red[tid] += red[tid + off]; __syncthreads(); }
    float inv1 = 1.f / sqrtf(red[0]);
    __syncthreads();
    if (blockIdx.x == 0) {
        float s0 = 0.f;
        for (int i = tid; i < 600; i += 256) s0 += f0[i] * f0[i];
        red[tid] = s0; __syncthreads();
        for (int off = 128; off; off >>= 1) { if (tid < off) red[tid] += red[tid + off]; __syncthreads(); }
        float inv0 = 1.f / sqrtf(red[0]);
        for (int i = tid; i < 600; i += 256) {
            int c = i / 25, k = i % 25;
            f0n[i] = f0[i] * inv0;
            f0t[i] = f0[c * 25 + (24 - k)] * inv0;
        }
    }
    int gid = blockIdx.x * 256 + tid;      // 6400 jobs
    int lane = gid & 63;
    int rest = gid >> 6;                   // 0..99
    int s = rest % KSTEPS;
    int md = rest / KSTEPS;                // 0..3
    int mode = md >> 1, m = md & 1;
    int o = m * 16 + (lane & 15);
    v8s av;
    #pragma unroll
    for (int j = 0; j < 8; ++j) {
        int c = 8 * (lane >> 4) + j;
        float wv = 0.f;
        if (o < CH && c < CH) {
            wv = (mode == 0) ? f1[(o * CH + c) * 25 + s]
                             : f1[(c * CH + o) * 25 + (24 - s)];
            wv *= inv1;
        }
        av[j] = f2bf(wv);
    }
    abuf[gid] = av;
}

// ---------------- fused A: conv1+rbf0 -> conv2 MFMA + rbf1 ---------------------
// 8x8 output tile, 1024 blocks, 4 blocks/CU. t1 stride 24 (2-way floor).
// stage-1: 432 jobs (3 ch-groups x 144 px) striped over all 256 threads.
__global__ __launch_bounds__(256, 4) void k_fuseA(const float* __restrict__ x,
        const float* __restrict__ f0n, const v8s* __restrict__ abuf,
        const float* __restrict__ mean, const float* __restrict__ aw0,
        const float* __restrict__ aw1, short* __restrict__ tb) {
    __shared__ float ws0[CH * NK];
    __shared__ float ws1[CH * NK];
    __shared__ float xs[256];
    __shared__ __align__(16) short t1[144 * T1S + 8];
    int tid = threadIdx.x;
    int x0 = blockIdx.x * 8, y0 = blockIdx.y * 8;
    {   // stage x window (16x16, clamped = replication pad)
        int r = tid >> 4, cL = tid & 15;
        int gy = min(max(y0 + r - 4, 0), H - 1);
        int gx = min(max(x0 + cL - 4, 0), W - 1);
        xs[tid] = x[gy * W + gx];
    }
    for (int i = tid; i < CH * NK; i += 256) { ws0[i] = aw0[i]; ws1[i] = aw1[i]; }
    RbfCtx ctx = make_ctx(mean);
    if (tid == 0) {   // tail pad: q=3 read of last pixel stays in-bounds
        v8s z = {0,0,0,0,0,0,0,0};
        *(v8s*)&t1[144 * T1S] = z;
    }
    __syncthreads();

    // stage 1: t1 = rbf0(conv1) on 12x12 haloed region; 432 jobs / 256 threads
    #pragma unroll 1
    for (int jb = tid; jb < 432; jb += 256) {
        int og = jb / 144;                  // channel group 0..2
        int px = jb - og * 144;
        int yi = (px * 5462) >> 16;         // px / 12
        int xi = px - yi * 12;
        int sy = min(max(y0 + yi - 2, 0), H - 1);
        int sx = min(max(x0 + xi - 2, 0), W - 1);
        int iy[5], ix[5];
        #pragma unroll
        for (int u = 0; u < 5; ++u) {
            iy[u] = min(max(sy + u - 2, 0), H - 1) - (y0 - 4);
            ix[u] = min(max(sx + u - 2, 0), W - 1) - (x0 - 4);
        }
        float in_[25];
        #pragma unroll
        for (int u = 0; u < 5; ++u)
            #pragma unroll
            for (int v = 0; v < 5; ++v) in_[u * 5 + v] = xs[iy[u] * 16 + ix[v]];
        v8s pk;
        #pragma unroll
        for (int oj = 0; oj < 8; ++oj) {
            int o = og * 8 + oj;
            float a = 0.f;
            #pragma unroll
            for (int k = 0; k < 25; ++k) a = fmaf(in_[k], f0n[o * 25 + k], a);
            pk[oj] = f2bf(rbf_eval<false>(a, ws0 + o * NK, ctx));
        }
        *(v8s*)&t1[px * T1S + og * 8] = pk;
    }
    __syncthreads();

    // stage 2: conv2 MFMA; wave = one 16-px N-tile (2 rows of 8)
    int lane = tid & 63, wv_ = tid >> 6;
    int p = lane & 15, q = lane >> 4;
    int row = (wv_ * 16 + p) >> 3, col = p & 7;
    const short* bbase = &t1[(row * 12 + col) * T1S + q * 8];
    v4f a0v = {0.f,0.f,0.f,0.f}, a1v = {0.f,0.f,0.f,0.f};
    #pragma unroll
    for (int s = 0; s < KSTEPS; ++s) {
        const int u = s / 5, v = s % 5;     // compile-time under full unroll
        v8s b   = *(const v8s*)&bbase[(u * 12 + v) * T1S];
        v8s af0 = abuf[s * 64 + lane];
        v8s af1 = abuf[1600 + s * 64 + lane];
        a0v = __builtin_amdgcn_mfma_f32_16x16x32_bf16(af0, b, a0v, 0, 0, 0);
        a1v = __builtin_amdgcn_mfma_f32_16x16x32_bf16(af1, b, a1v, 0, 0, 0);
    }
    // epilogue: rbf1 -> tb[pix][ch] (channel-minor), 8B stores
    int pix = (y0 + row) * W + (x0 + col);
    v4s st;
    #pragma unroll
    for (int j = 0; j < 4; ++j)
        st[j] = f2bf(rbf_eval<false>(a0v[j], ws1 + (q * 4 + j) * NK, ctx));
    *(v4s*)&tb[pix * 24 + q * 4] = st;
    if (q < 2) {
        #pragma unroll
        for (int j = 0; j < 4; ++j)
            st[j] = f2bf(rbf_eval<false>(a1v[j], ws1 + (16 + q * 4 + j) * NK, ctx));
        *(v4s*)&tb[pix * 24 + 16 + q * 4] = st;
    }
}

// ---------------- fused B: convT2 MFMA + rbf' -> convT1 + final ----------------
// 8x8 output tile, 1024 blocks, 4 blocks/CU (33 KB LDS).
// tbt stride 24 (2-way floor); tiles distributed (3,2,2,2) across waves.
__global__ __launch_bounds__(256, 4) void k_fuseB(const short* __restrict__ tb,
        const v8s* __restrict__ abuf, const float* __restrict__ f0t,
        const float* __restrict__ mean, const float* __restrict__ aw0,
        const float* __restrict__ x, const float* __restrict__ y,
        const float* __restrict__ lamp, float* __restrict__ out) {
    __shared__ float ws0[CH * NK];
    __shared__ __align__(16) short tbt[256 * TBS + 8];  // reused as red[] in ph4
    __shared__ float t3[144 * T3S];
    int tid = threadIdx.x;
    int x0 = blockIdx.x * 8, y0 = blockIdx.y * 8;
    {   // stage tb window: 16x16 px, zero pad outside image
        int r = tid >> 4, cL = tid & 15;
        int gy = y0 + r - 4, gx = x0 + cL - 4;
        v8s z = {0,0,0,0,0,0,0,0};
        if (gy >= 0 && gy < H && gx >= 0 && gx < W) {
            const v8s* src = (const v8s*)&tb[(gy * W + gx) * 24];
            *(v8s*)&tbt[tid * TBS]      = src[0];
            *(v8s*)&tbt[tid * TBS + 8]  = src[1];
            *(v8s*)&tbt[tid * TBS + 16] = src[2];
        } else {
            *(v8s*)&tbt[tid * TBS]      = z;
            *(v8s*)&tbt[tid * TBS + 8]  = z;
            *(v8s*)&tbt[tid * TBS + 16] = z;
        }
        if (tid == 0) *(v8s*)&tbt[256 * TBS] = z;   // tail pad (q=3, last px)
    }
    for (int i = tid; i < CH * NK; i += 256) ws0[i] = aw0[i];
    RbfCtx ctx = make_ctx(mean);
    __syncthreads();

    // convT2 MFMA (mode-1 A-frags): wave w owns tiles {w, w+4, w+8} -> (3,2,2,2)
    int lane = tid & 63, wv_ = tid >> 6;
    int p = lane & 15, q = lane >> 4;
    const v8s* ap = abuf + 3200;
    int base[3], frow[3], fcol[3];
    bool valid[3];
    #pragma unroll
    for (int g = 0; g < 3; ++g) {
        int tIdx = wv_ + 4 * g;
        valid[g] = (tIdx <= 8);
        int tc = valid[g] ? tIdx : 8;
        int f = tc * 16 + p;                 // flat t3 px < 144
        int r_ = (f * 5462) >> 16;           // f / 12
        frow[g] = r_; fcol[g] = f - r_ * 12;
        base[g] = (r_ * 16 + fcol[g]) * TBS + q * 8;
    }
    v4f acc0[3], acc1[3];
    #pragma unroll
    for (int g = 0; g < 3; ++g) { acc0[g] = (v4f){0.f,0.f,0.f,0.f}; acc1[g] = (v4f){0.f,0.f,0.f,0.f}; }
    #pragma unroll
    for (int s = 0; s < KSTEPS; ++s) {
        const int off = ((s / 5) * 16 + (s % 5)) * TBS;   // compile-time
        v8s af0 = ap[s * 64 + lane];
        v8s af1 = ap[1600 + s * 64 + lane];
        #pragma unroll
        for (int g = 0; g < 3; ++g) {
            v8s b = *(const v8s*)&tbt[base[g] + off];
            acc0[g] = __builtin_amdgcn_mfma_f32_16x16x32_bf16(af0, b, acc0[g], 0, 0, 0);
            acc1[g] = __builtin_amdgcn_mfma_f32_16x16x32_bf16(af1, b, acc1[g], 0, 0, 0);
        }
    }
    // rbf_der -> t3 (zero outside image)
    #pragma unroll
    for (int g = 0; g < 3; ++g) {
        if (valid[g]) {
            int f = (wv_ + 4 * g) * 16 + p;
            int gy = y0 + frow[g] - 2, gx = x0 + fcol[g] - 2;
            bool inimg = (gy >= 0 && gy < H && gx >= 0 && gx < W);
            #pragma unroll
            for (int j = 0; j < 4; ++j)
                t3[f * T3S + q * 4 + j] =
                    inimg ? rbf_eval<true>(acc0[g][j], ws0 + (q * 4 + j) * NK, ctx) : 0.f;
            if (q < 2) {
                #pragma unroll
                for (int j = 0; j < 4; ++j)
                    t3[f * T3S + 16 + q * 4 + j] =
                        inimg ? rbf_eval<true>(acc1[g][j], ws0 + (16 + q * 4 + j) * NK, ctx) : 0.f;
            }
        }
    }
    __syncthreads();   // tbt fully consumed; reuse as reduction buffer

    // convT1 (24->1, pre-flipped f0t) + final; 4-way channel split across waves
    float* red = (float*)tbt;
    int gq = __builtin_amdgcn_readfirstlane(tid >> 6);
    int px = tid & 63, pr = px >> 3, pc = px & 7;
    float a = 0.f;
    #pragma unroll 1
    for (int cp = 0; cp < 3; ++cp) {
        int c = gq * 6 + cp * 2;               // even -> 8B-aligned float2
        const float* fb0 = f0t + c * 25;
        const float* fb1 = f0t + (c + 1) * 25;
        #pragma unroll
        for (int u = 0; u < 5; ++u)
            #pragma unroll
            for (int v = 0; v < 5; ++v) {
                float2 tp = *(const float2*)&t3[((pr + u) * 12 + (pc + v)) * T3S + c];
                a = fmaf(tp.x, fb0[u * 5 + v], a);
                a = fmaf(tp.y, fb1[u * 5 + v], a);
            }
    }
    red[tid] = a;
    __syncthreads();
    if (tid < 64) {
        float tot = red[tid] + red[64 + tid] + red[128 + tid] + red[192 + tid];
        int pix = (y0 + pr) * W + (x0 + pc);
        float elam = __expf(lamp[0]);
        float xv = x[pix], yv = y[pix];
        out[pix] = xv - (tot + elam * (xv - yv));
    }
}

extern "C" void kernel_launch(void* const* d_in, const int* in_sizes, int n_in,
                              void* d_out, int out_size, void* d_ws, size_t ws_size,
                              hipStream_t stream) {
    const float* x    = (const float*)d_in[0];
    const float* y    = (const float*)d_in[1];
    const float* f0   = (const float*)d_in[3];
    const float* f1   = (const float*)d_in[4];
    const float* aw0  = (const float*)d_in[5];
    const float* aw1  = (const float*)d_in[6];
    const float* mean = (const float*)d_in[7];
    const float* lamp = (const float*)d_in[8];
    float* out = (float*)d_out;

    float* w   = (float*)d_ws;
    float* f0n = w;                  // 600
    float* f0t = w + 640;            // 600
    v8s*  abuf = (v8s*)(w + 1536);   // 6400 * 16 B
    short* tb  = (short*)(w + 32768);

    k_prep<<<25, 256, 0, stream>>>(f0, f1, f0n, f0t, abuf);
    dim3 grid(W / 8, H / 8);         // 32 x 32 = 1024 blocks
    k_fuseA<<<grid, 256, 0, stream>>>(x, f0n, abuf, mean, aw0, aw1, tb);
    k_fuseB<<<grid, 256, 0, stream>>>(tb, abuf, f0t, mean, aw0, x, y, lamp, out);
}

// Round 18
// 56.393 us; speedup vs baseline: 1.0486x; 1.0486x over previous
//
#include <hip/hip_runtime.h>
#include <math.h>

#define H 256
#define W 256
#define HW (H * W)
#define CH 24
#define NK 63
#define T1S 24          // t1 per-pixel stride in shorts (48 B = 12 dwords, 2-way floor)
#define TBS 24          // tbt per-pixel stride in shorts
#define KSTEPS 25       // K = 25 taps * 32 (24 ch + 8 zero-pad)
#define NE 257          // table dwords per channel (pairs of 258 samples)
#define TBLN (CH * NE)  // 6168 dwords per table
#define T3S 26          // t3 per-pixel stride in floats

typedef short v8s __attribute__((ext_vector_type(8)));
typedef short v4s __attribute__((ext_vector_type(4)));
typedef float v4f __attribute__((ext_vector_type(4)));

// ---------------- bf16 helper ----------------------------------------------------
__device__ __forceinline__ short f2bf(float v) {
    unsigned u = __float_as_uint(v);
    u += 0x7fff + ((u >> 16) & 1);
    return (short)(u >> 16);
}

// ---------------- table lookup (global, L1-resident) ------------------------------
struct TblCtx { float off, invh; };
__device__ __forceinline__ TblCtx make_tctx(const float* __restrict__ mean) {
    TblCtx c;
    float lo = mean[0] - 12.f;
    float hi = mean[NK - 1] + 12.f;
    c.invh = 257.f / (hi - lo);
    c.off  = -lo * c.invh;
    return c;
}
__device__ __forceinline__ float tbl_eval(const unsigned* __restrict__ tbl, int ch,
                                          float v, const TblCtx& c) {
    float t = fmaf(v, c.invh, c.off);
    t = fminf(fmaxf(t, 0.f), 256.999f);
    float fi = floorf(t);
    float fr = t - fi;
    unsigned u = tbl[ch * NE + (int)fi];        // global dword, L1-hit
    float a = __uint_as_float(u << 16);
    float b = __uint_as_float(u & 0xffff0000u);
    return fmaf(fr, b - a, a);
}

// ---------------- prep: norms, f0n/f0t, A-frag pack, RBF tables --------------------
// abuf: [mode 2][mtile 2][kstep 25][lane 64] v8s. k = tap*32 + c (c<24, pad=0).
// tables: tg[tt][ch][NE], tt: 0=rbf(aw0), 1=rbf(aw1), 2=rbf_der(aw0); exact 63-tap.
__global__ void k_prep(const float* __restrict__ f0, const float* __restrict__ f1,
                       const float* __restrict__ mean, const float* __restrict__ aw0,
                       const float* __restrict__ aw1,
                       float* __restrict__ f0n, float* __restrict__ f0t,
                       v8s* __restrict__ abuf, unsigned* __restrict__ tg) {
    __shared__ float red[256];
    int tid = threadIdx.x;
    float s1 = 0.f;
    for (int i = tid; i < 14400; i += 256) s1 += f1[i] * f1[i];
    red[tid] = s1; __syncthreads();
    for (int off = 128; off; off >>= 1) { if (tid < off) red[tid] += red[tid + off]; __syncthreads(); }
    float inv1 = 1.f / sqrtf(red[0]);
    __syncthreads();
    if (blockIdx.x == 0) {
        float s0 = 0.f;
        for (int i = tid; i < 600; i += 256) s0 += f0[i] * f0[i];
        red[tid] = s0; __syncthreads();
        for (int off = 128; off; off >>= 1) { if (tid < off) red[tid] += red[tid + off]; __syncthreads(); }
        float inv0 = 1.f / sqrtf(red[0]);
        for (int i = tid; i < 600; i += 256) {
            int c = i / 25, k = i % 25;
            f0n[i] = f0[i] * inv0;
            f0t[i] = f0[c * 25 + (24 - k)] * inv0;
        }
    }
    int gid = blockIdx.x * 256 + tid;      // 75 blocks -> 19200 threads
    if (gid < 6400) {                      // A-fragment pack
        int lane = gid & 63;
        int rest = gid >> 6;               // 0..99
        int s = rest % KSTEPS;
        int md = rest / KSTEPS;            // 0..3
        int mode = md >> 1, m = md & 1;
        int o = m * 16 + (lane & 15);
        v8s av;
        #pragma unroll
        for (int j = 0; j < 8; ++j) {
            int c = 8 * (lane >> 4) + j;
            float wv = 0.f;
            if (o < CH && c < CH) {
                wv = (mode == 0) ? f1[(o * CH + c) * 25 + s]
                                 : f1[(c * CH + o) * 25 + (24 - s)];
                wv *= inv1;
            }
            av[j] = f2bf(wv);
        }
        abuf[gid] = av;
    }
    // RBF tables: 18504 jobs, one per thread; exact 63-tap sums
    float lo = mean[0] - 12.f;
    float hi = mean[NK - 1] + 12.f;
    float h  = (hi - lo) * (1.f / 257.f);
    if (gid < 3 * TBLN) {
        int tt = gid / TBLN;
        int rest = gid - tt * TBLN;
        int ch = rest / NE;
        int i  = rest - ch * NE;
        const float* wr = ((tt == 1) ? aw1 : aw0) + ch * NK;
        float v0 = fmaf(h, (float)i, lo);
        float v1 = v0 + h;
        float s0 = 0.f, s1v = 0.f;
        for (int k = 0; k < NK; ++k) {
            float m = mean[k], wk = wr[k];
            float d0 = v0 - m, d1 = v1 - m;
            float e0 = __expf(d0 * d0 * -0.005f);
            float e1 = __expf(d1 * d1 * -0.005f);
            if (tt == 2) { e0 *= d0 * -0.01f; e1 *= d1 * -0.01f; }
            s0 = fmaf(e0, wk, s0);
            s1v = fmaf(e1, wk, s1v);
        }
        unsigned pb = ((unsigned)(unsigned short)f2bf(s1v) << 16)
                    | (unsigned)(unsigned short)f2bf(s0);
        tg[gid] = pb;
    }
}

// ---------------- fused A: conv1+rbf0(T0) -> conv2 MFMA + rbf1(T1) -----------------
// 8x8 output tile, 1024 blocks, 4 blocks/CU. t1 stride 24 (2-way floor); 8 KB LDS.
__global__ __launch_bounds__(256, 4) void k_fuseA(const float* __restrict__ x,
        const float* __restrict__ f0n, const v8s* __restrict__ abuf,
        const float* __restrict__ mean, const unsigned* __restrict__ T0g,
        const unsigned* __restrict__ T1g, short* __restrict__ tb) {
    __shared__ float xs[256];
    __shared__ __align__(16) short t1[144 * T1S + 8];
    int tid = threadIdx.x;
    int x0 = blockIdx.x * 8, y0 = blockIdx.y * 8;
    {   // stage x window (16x16, clamped = replication pad)
        int r = tid >> 4, cL = tid & 15;
        int gy = min(max(y0 + r - 4, 0), H - 1);
        int gx = min(max(x0 + cL - 4, 0), W - 1);
        xs[tid] = x[gy * W + gx];
    }
    TblCtx ctx = make_tctx(mean);
    if (tid == 0) {   // tail pad: q=3 read of last pixel stays in-bounds
        v8s z = {0,0,0,0,0,0,0,0};
        *(v8s*)&t1[144 * T1S] = z;
    }
    __syncthreads();

    // stage 1: t1 = rbf0(conv1) on 12x12 haloed region; 432 jobs / 256 threads
    #pragma unroll 1
    for (int jb = tid; jb < 432; jb += 256) {
        int og = jb / 144;                  // channel group 0..2
        int px = jb - og * 144;
        int yi = (px * 5462) >> 16;         // px / 12
        int xi = px - yi * 12;
        int sy = min(max(y0 + yi - 2, 0), H - 1);
        int sx = min(max(x0 + xi - 2, 0), W - 1);
        int iy[5], ix[5];
        #pragma unroll
        for (int u = 0; u < 5; ++u) {
            iy[u] = min(max(sy + u - 2, 0), H - 1) - (y0 - 4);
            ix[u] = min(max(sx + u - 2, 0), W - 1) - (x0 - 4);
        }
        float in_[25];
        #pragma unroll
        for (int u = 0; u < 5; ++u)
            #pragma unroll
            for (int v = 0; v < 5; ++v) in_[u * 5 + v] = xs[iy[u] * 16 + ix[v]];
        v8s pk;
        #pragma unroll
        for (int oj = 0; oj < 8; ++oj) {
            int o = og * 8 + oj;
            float a = 0.f;
            #pragma unroll
            for (int k = 0; k < 25; ++k) a = fmaf(in_[k], f0n[o * 25 + k], a);
            pk[oj] = f2bf(tbl_eval(T0g, o, a, ctx));
        }
        *(v8s*)&t1[px * T1S + og * 8] = pk;
    }
    __syncthreads();

    // stage 2: conv2 MFMA; wave = one 16-px N-tile (2 rows of 8)
    int lane = tid & 63, wv_ = tid >> 6;
    int p = lane & 15, q = lane >> 4;
    int row = (wv_ * 16 + p) >> 3, col = p & 7;
    const short* bbase = &t1[(row * 12 + col) * T1S + q * 8];
    v4f a0v = {0.f,0.f,0.f,0.f}, a1v = {0.f,0.f,0.f,0.f};
    #pragma unroll
    for (int s = 0; s < KSTEPS; ++s) {
        const int u = s / 5, v = s % 5;     // compile-time under full unroll
        v8s b   = *(const v8s*)&bbase[(u * 12 + v) * T1S];
        v8s af0 = abuf[s * 64 + lane];
        v8s af1 = abuf[1600 + s * 64 + lane];
        a0v = __builtin_amdgcn_mfma_f32_16x16x32_bf16(af0, b, a0v, 0, 0, 0);
        a1v = __builtin_amdgcn_mfma_f32_16x16x32_bf16(af1, b, a1v, 0, 0, 0);
    }
    // epilogue: rbf1 via T1 -> tb[pix][ch] (channel-minor), 8B stores
    int pix = (y0 + row) * W + (x0 + col);
    v4s st;
    #pragma unroll
    for (int j = 0; j < 4; ++j)
        st[j] = f2bf(tbl_eval(T1g, q * 4 + j, a0v[j], ctx));
    *(v4s*)&tb[pix * 24 + q * 4] = st;
    if (q < 2) {
        #pragma unroll
        for (int j = 0; j < 4; ++j)
            st[j] = f2bf(tbl_eval(T1g, 16 + q * 4 + j, a1v[j], ctx));
        *(v4s*)&tb[pix * 24 + 16 + q * 4] = st;
    }
}

// ---------------- fused B: convT2 MFMA + rbf'(TD) -> convT1 + final ----------------
// 8x8 output tile, 1024 blocks, 4 blocks/CU (27 KB LDS).
// tbt stride 24 (2-way floor); tiles distributed (3,2,2,2) across waves.
__global__ __launch_bounds__(256, 4) void k_fuseB(const short* __restrict__ tb,
        const v8s* __restrict__ abuf, const float* __restrict__ f0t,
        const float* __restrict__ mean, const unsigned* __restrict__ TDg,
        const float* __restrict__ x, const float* __restrict__ y,
        const float* __restrict__ lamp, float* __restrict__ out) {
    __shared__ __align__(16) short tbt[256 * TBS + 8];  // reused as red[] in ph4
    __shared__ float t3[144 * T3S];
    int tid = threadIdx.x;
    int x0 = blockIdx.x * 8, y0 = blockIdx.y * 8;
    {   // stage tb window: 16x16 px, zero pad outside image
        int r = tid >> 4, cL = tid & 15;
        int gy = y0 + r - 4, gx = x0 + cL - 4;
        v8s z = {0,0,0,0,0,0,0,0};
        if (gy >= 0 && gy < H && gx >= 0 && gx < W) {
            const v8s* src = (const v8s*)&tb[(gy * W + gx) * 24];
            *(v8s*)&tbt[tid * TBS]      = src[0];
            *(v8s*)&tbt[tid * TBS + 8]  = src[1];
            *(v8s*)&tbt[tid * TBS + 16] = src[2];
        } else {
            *(v8s*)&tbt[tid * TBS]      = z;
            *(v8s*)&tbt[tid * TBS + 8]  = z;
            *(v8s*)&tbt[tid * TBS + 16] = z;
        }
        if (tid == 0) *(v8s*)&tbt[256 * TBS] = z;   // tail pad (q=3, last px)
    }
    TblCtx ctx = make_tctx(mean);
    __syncthreads();

    // convT2 MFMA (mode-1 A-frags): wave w owns tiles {w, w+4, w+8} -> (3,2,2,2)
    int lane = tid & 63, wv_ = tid >> 6;
    int p = lane & 15, q = lane >> 4;
    const v8s* ap = abuf + 3200;
    int base[3], frow[3], fcol[3];
    bool valid[3];
    #pragma unroll
    for (int g = 0; g < 3; ++g) {
        int tIdx = wv_ + 4 * g;
        valid[g] = (tIdx <= 8);
        int tc = valid[g] ? tIdx : 8;
        int f = tc * 16 + p;                 // flat t3 px < 144
        int r_ = (f * 5462) >> 16;           // f / 12
        frow[g] = r_; fcol[g] = f - r_ * 12;
        base[g] = (r_ * 16 + fcol[g]) * TBS + q * 8;
    }
    v4f acc0[3], acc1[3];
    #pragma unroll
    for (int g = 0; g < 3; ++g) { acc0[g] = (v4f){0.f,0.f,0.f,0.f}; acc1[g] = (v4f){0.f,0.f,0.f,0.f}; }
    #pragma unroll
    for (int s = 0; s < KSTEPS; ++s) {
        const int off = ((s / 5) * 16 + (s % 5)) * TBS;   // compile-time
        v8s af0 = ap[s * 64 + lane];
        v8s af1 = ap[1600 + s * 64 + lane];
        #pragma unroll
        for (int g = 0; g < 3; ++g) {
            v8s b = *(const v8s*)&tbt[base[g] + off];
            acc0[g] = __builtin_amdgcn_mfma_f32_16x16x32_bf16(af0, b, acc0[g], 0, 0, 0);
            acc1[g] = __builtin_amdgcn_mfma_f32_16x16x32_bf16(af1, b, acc1[g], 0, 0, 0);
        }
    }
    // rbf_der via TD -> t3 (zero outside image)
    #pragma unroll
    for (int g = 0; g < 3; ++g) {
        if (valid[g]) {
            int f = (wv_ + 4 * g) * 16 + p;
            int gy = y0 + frow[g] - 2, gx = x0 + fcol[g] - 2;
            bool inimg = (gy >= 0 && gy < H && gx >= 0 && gx < W);
            #pragma unroll
            for (int j = 0; j < 4; ++j)
                t3[f * T3S + q * 4 + j] =
                    inimg ? tbl_eval(TDg, q * 4 + j, acc0[g][j], ctx) : 0.f;
            if (q < 2) {
                #pragma unroll
                for (int j = 0; j < 4; ++j)
                    t3[f * T3S + 16 + q * 4 + j] =
                        inimg ? tbl_eval(TDg, 16 + q * 4 + j, acc1[g][j], ctx) : 0.f;
            }
        }
    }
    __syncthreads();   // tbt fully consumed; reuse as reduction buffer

    // convT1 (24->1, pre-flipped f0t) + final; 4-way channel split across waves
    float* red = (float*)tbt;
    int gq = __builtin_amdgcn_readfirstlane(tid >> 6);
    int px = tid & 63, pr = px >> 3, pc = px & 7;
    float a = 0.f;
    #pragma unroll 1
    for (int cp = 0; cp < 3; ++cp) {
        int c = gq * 6 + cp * 2;               // even -> 8B-aligned float2
        const float* fb0 = f0t + c * 25;
        const float* fb1 = f0t + (c + 1) * 25;
        #pragma unroll
        for (int u = 0; u < 5; ++u)
            #pragma unroll
            for (int v = 0; v < 5; ++v) {
                float2 tp = *(const float2*)&t3[((pr + u) * 12 + (pc + v)) * T3S + c];
                a = fmaf(tp.x, fb0[u * 5 + v], a);
                a = fmaf(tp.y, fb1[u * 5 + v], a);
            }
    }
    red[tid] = a;
    __syncthreads();
    if (tid < 64) {
        float tot = red[tid] + red[64 + tid] + red[128 + tid] + red[192 + tid];
        int pix = (y0 + pr) * W + (x0 + pc);
        float elam = __expf(lamp[0]);
        float xv = x[pix], yv = y[pix];
        out[pix] = xv - (tot + elam * (xv - yv));
    }
}

extern "C" void kernel_launch(void* const* d_in, const int* in_sizes, int n_in,
                              void* d_out, int out_size, void* d_ws, size_t ws_size,
                              hipStream_t stream) {
    const float* x    = (const float*)d_in[0];
    const float* y    = (const float*)d_in[1];
    const float* f0   = (const float*)d_in[3];
    const float* f1   = (const float*)d_in[4];
    const float* aw0  = (const float*)d_in[5];
    const float* aw1  = (const float*)d_in[6];
    const float* mean = (const float*)d_in[7];
    const float* lamp = (const float*)d_in[8];
    float* out = (float*)d_out;

    float* w   = (float*)d_ws;
    float* f0n = w;                          // 600
    float* f0t = w + 640;                    // 600
    v8s*  abuf = (v8s*)(w + 1536);           // 6400*16B -> ends at w+27136
    unsigned* tg = (unsigned*)(w + 27136);   // 3*6168 dwords
    unsigned* T0g = tg;
    unsigned* T1g = tg + TBLN;
    unsigned* TDg = tg + 2 * TBLN;
    short* tb  = (short*)(w + 46080);        // 1.57M shorts

    k_prep<<<75, 256, 0, stream>>>(f0, f1, mean, aw0, aw1, f0n, f0t, abuf, tg);
    dim3 grid(W / 8, H / 8);                 // 32 x 32 = 1024 blocks
    k_fuseA<<<grid, 256, 0, stream>>>(x, f0n, abuf, mean, T0g, T1g, tb);
    k_fuseB<<<grid, 256, 0, stream>>>(tb, abuf, f0t, mean, TDg, x, y, lamp, out);
}

// Round 19
// 53.604 us; speedup vs baseline: 1.1032x; 1.0520x over previous
//
#include <hip/hip_runtime.h>
#include <math.h>

#define H 256
#define W 256
#define HW (H * W)
#define CH 24
#define NK 63
#define T1S 24          // t1 per-pixel stride in shorts (48 B = 12 dwords, 2-way floor)
#define TBS 24          // tbt per-pixel stride in shorts
#define KSTEPS 19       // K = 600 packed (tap*24 + c), padded to 608
#define NE 257          // table dwords per channel (pairs of 258 samples)
#define TBLN (CH * NE)  // 6168 dwords per table
#define T3S 26          // t3 per-pixel stride in floats

typedef short v8s __attribute__((ext_vector_type(8)));
typedef short v4s __attribute__((ext_vector_type(4)));
typedef float v4f __attribute__((ext_vector_type(4)));

// ---------------- bf16 helper ----------------------------------------------------
__device__ __forceinline__ short f2bf(float v) {
    unsigned u = __float_as_uint(v);
    u += 0x7fff + ((u >> 16) & 1);
    return (short)(u >> 16);
}

// ---------------- table lookup (global, L1-resident) ------------------------------
struct TblCtx { float off, invh; };
__device__ __forceinline__ TblCtx make_tctx(const float* __restrict__ mean) {
    TblCtx c;
    float lo = mean[0] - 12.f;
    float hi = mean[NK - 1] + 12.f;
    c.invh = 257.f / (hi - lo);
    c.off  = -lo * c.invh;
    return c;
}
__device__ __forceinline__ float tbl_eval(const unsigned* __restrict__ tbl, int ch,
                                          float v, const TblCtx& c) {
    float t = fmaf(v, c.invh, c.off);
    t = fminf(fmaxf(t, 0.f), 256.999f);
    float fi = floorf(t);
    float fr = t - fi;
    unsigned u = tbl[ch * NE + (int)fi];        // global dword, L1-hit
    float a = __uint_as_float(u << 16);
    float b = __uint_as_float(u & 0xffff0000u);
    return fmaf(fr, b - a, a);
}

// ---------------- packed-K index helper: k = tap*24 + c, K 600->608 ----------------
// k0 = 32s + 8q  ->  t = k0/24, c0 = k0%24 (in {0,8,16}), u = t/5, v = t%5
__device__ __forceinline__ void kidx(int s, int q, int& t, int& c0, int& u, int& v) {
    int k0 = 32 * s + (q << 3);
    t  = (k0 * 2731) >> 16;        // k0/24, exact for k0 < 16379
    c0 = k0 - t * 24;
    u  = (t * 3277) >> 14;         // t/5, exact for t <= 26
    v  = t - u * 5;
}

// ---------------- prep: norms, f0n/f0t, A-frag pack, RBF tables --------------------
// abuf: [mode 2][mtile 2][kstep 19][lane 64] v8s (4864 total). k = tap*24 + c.
// tables: tg[tt][ch][NE], tt: 0=rbf(aw0), 1=rbf(aw1), 2=rbf_der(aw0); exact 63-tap.
__global__ void k_prep(const float* __restrict__ f0, const float* __restrict__ f1,
                       const float* __restrict__ mean, const float* __restrict__ aw0,
                       const float* __restrict__ aw1,
                       float* __restrict__ f0n, float* __restrict__ f0t,
                       v8s* __restrict__ abuf, unsigned* __restrict__ tg) {
    __shared__ float red[256];
    int tid = threadIdx.x;
    float s1 = 0.f;
    for (int i = tid; i < 14400; i += 256) s1 += f1[i] * f1[i];
    red[tid] = s1; __syncthreads();
    for (int off = 128; off; off >>= 1) { if (tid < off) red[tid] += red[tid + off]; __syncthreads(); }
    float inv1 = 1.f / sqrtf(red[0]);
    __syncthreads();
    if (blockIdx.x == 0) {
        float s0 = 0.f;
        for (int i = tid; i < 600; i += 256) s0 += f0[i] * f0[i];
        red[tid] = s0; __syncthreads();
        for (int off = 128; off; off >>= 1) { if (tid < off) red[tid] += red[tid + off]; __syncthreads(); }
        float inv0 = 1.f / sqrtf(red[0]);
        for (int i = tid; i < 600; i += 256) {
            int c = i / 25, k = i % 25;
            f0n[i] = f0[i] * inv0;
            f0t[i] = f0[c * 25 + (24 - k)] * inv0;
        }
    }
    int gid = blockIdx.x * 256 + tid;      // 75 blocks -> 19200 threads
    if (gid < 4864) {                      // A-fragment pack (19 steps)
        int lane = gid & 63;
        int rest = gid >> 6;               // 0..75
        int s = rest % KSTEPS;
        int md = rest / KSTEPS;            // 0..3
        int mode = md >> 1, m = md & 1;
        int o = m * 16 + (lane & 15);
        v8s av;
        #pragma unroll
        for (int j = 0; j < 8; ++j) {
            int k = 32 * s + 8 * (lane >> 4) + j;
            float wv = 0.f;
            if (o < CH && k < 600) {
                int t = k / 24, c = k - (k / 24) * 24;
                wv = (mode == 0) ? f1[(o * CH + c) * 25 + t]
                                 : f1[(c * CH + o) * 25 + (24 - t)];
                wv *= inv1;
            }
            av[j] = f2bf(wv);
        }
        abuf[gid] = av;
    }
    // RBF tables: 18504 jobs, one per thread; exact 63-tap sums
    float lo = mean[0] - 12.f;
    float hi = mean[NK - 1] + 12.f;
    float h  = (hi - lo) * (1.f / 257.f);
    if (gid < 3 * TBLN) {
        int tt = gid / TBLN;
        int rest = gid - tt * TBLN;
        int ch = rest / NE;
        int i  = rest - ch * NE;
        const float* wr = ((tt == 1) ? aw1 : aw0) + ch * NK;
        float v0 = fmaf(h, (float)i, lo);
        float v1 = v0 + h;
        float s0 = 0.f, s1v = 0.f;
        for (int k = 0; k < NK; ++k) {
            float m = mean[k], wk = wr[k];
            float d0 = v0 - m, d1 = v1 - m;
            float e0 = __expf(d0 * d0 * -0.005f);
            float e1 = __expf(d1 * d1 * -0.005f);
            if (tt == 2) { e0 *= d0 * -0.01f; e1 *= d1 * -0.01f; }
            s0 = fmaf(e0, wk, s0);
            s1v = fmaf(e1, wk, s1v);
        }
        unsigned pb = ((unsigned)(unsigned short)f2bf(s1v) << 16)
                    | (unsigned)(unsigned short)f2bf(s0);
        tg[gid] = pb;
    }
}

// ---------------- fused A: conv1+rbf0(T0) -> conv2 MFMA + rbf1(T1) -----------------
// 8x8 output tile, 1024 blocks, 4 blocks/CU. t1: 144 px + 8 zero-pad px (tail u=5).
__global__ __launch_bounds__(256, 4) void k_fuseA(const float* __restrict__ x,
        const float* __restrict__ f0n, const v8s* __restrict__ abuf,
        const float* __restrict__ mean, const unsigned* __restrict__ T0g,
        const unsigned* __restrict__ T1g, short* __restrict__ tb) {
    __shared__ float xs[256];
    __shared__ __align__(16) short t1[152 * T1S];   // 144 real + 8 pad px
    int tid = threadIdx.x;
    int x0 = blockIdx.x * 8, y0 = blockIdx.y * 8;
    {   // stage x window (16x16, clamped = replication pad)
        int r = tid >> 4, cL = tid & 15;
        int gy = min(max(y0 + r - 4, 0), H - 1);
        int gx = min(max(x0 + cL - 4, 0), W - 1);
        xs[tid] = x[gy * W + gx];
    }
    TblCtx ctx = make_tctx(mean);
    if (tid < 24) {   // zero the 8 pad pixels (24 v8s)
        v8s z = {0,0,0,0,0,0,0,0};
        *(v8s*)&t1[144 * T1S + tid * 8] = z;
    }
    __syncthreads();

    // stage 1: t1 = rbf0(conv1) on 12x12 haloed region; 432 jobs / 256 threads
    #pragma unroll 1
    for (int jb = tid; jb < 432; jb += 256) {
        int og = jb / 144;                  // channel group 0..2
        int px = jb - og * 144;
        int yi = (px * 5462) >> 16;         // px / 12
        int xi = px - yi * 12;
        int sy = min(max(y0 + yi - 2, 0), H - 1);
        int sx = min(max(x0 + xi - 2, 0), W - 1);
        int iy[5], ix[5];
        #pragma unroll
        for (int u = 0; u < 5; ++u) {
            iy[u] = min(max(sy + u - 2, 0), H - 1) - (y0 - 4);
            ix[u] = min(max(sx + u - 2, 0), W - 1) - (x0 - 4);
        }
        float in_[25];
        #pragma unroll
        for (int u = 0; u < 5; ++u)
            #pragma unroll
            for (int v = 0; v < 5; ++v) in_[u * 5 + v] = xs[iy[u] * 16 + ix[v]];
        v8s pk;
        #pragma unroll
        for (int oj = 0; oj < 8; ++oj) {
            int o = og * 8 + oj;
            float a = 0.f;
            #pragma unroll
            for (int k = 0; k < 25; ++k) a = fmaf(in_[k], f0n[o * 25 + k], a);
            pk[oj] = f2bf(tbl_eval(T0g, o, a, ctx));
        }
        *(v8s*)&t1[px * T1S + og * 8] = pk;
    }
    __syncthreads();

    // stage 2: conv2 MFMA; wave = one 16-px N-tile (2 rows of 8); K packed 608
    int lane = tid & 63, wv_ = tid >> 6;
    int p = lane & 15, q = lane >> 4;
    int row = (wv_ * 16 + p) >> 3, col = p & 7;
    int pxbase = row * 12 + col;
    v4f a0v = {0.f,0.f,0.f,0.f}, a1v = {0.f,0.f,0.f,0.f};
    #pragma unroll
    for (int s = 0; s < KSTEPS; ++s) {
        int t, c0, u, v;
        kidx(s, q, t, c0, u, v);
        v8s b   = *(const v8s*)&t1[(pxbase + u * 12 + v) * T1S + c0];
        v8s af0 = abuf[s * 64 + lane];
        v8s af1 = abuf[1216 + s * 64 + lane];
        a0v = __builtin_amdgcn_mfma_f32_16x16x32_bf16(af0, b, a0v, 0, 0, 0);
        a1v = __builtin_amdgcn_mfma_f32_16x16x32_bf16(af1, b, a1v, 0, 0, 0);
    }
    // epilogue: rbf1 via T1 -> tb[pix][ch] (channel-minor), 8B stores
    int pix = (y0 + row) * W + (x0 + col);
    v4s st;
    #pragma unroll
    for (int j = 0; j < 4; ++j)
        st[j] = f2bf(tbl_eval(T1g, q * 4 + j, a0v[j], ctx));
    *(v4s*)&tb[pix * 24 + q * 4] = st;
    if (q < 2) {
        #pragma unroll
        for (int j = 0; j < 4; ++j)
            st[j] = f2bf(tbl_eval(T1g, 16 + q * 4 + j, a1v[j], ctx));
        *(v4s*)&tb[pix * 24 + 16 + q * 4] = st;
    }
}

// ---------------- fused B: convT2 MFMA + rbf'(TD) -> convT1 + final ----------------
// 8x8 output tile, 1024 blocks, 4 blocks/CU. tbt: 256 px + 16 zero-pad px.
// tiles distributed (3,2,2,2) across waves; K packed 608.
__global__ __launch_bounds__(256, 4) void k_fuseB(const short* __restrict__ tb,
        const v8s* __restrict__ abuf, const float* __restrict__ f0t,
        const float* __restrict__ mean, const unsigned* __restrict__ TDg,
        const float* __restrict__ x, const float* __restrict__ y,
        const float* __restrict__ lamp, float* __restrict__ out) {
    __shared__ __align__(16) short tbt[272 * TBS];  // 256 real + 16 pad px; red[] in ph4
    __shared__ float t3[144 * T3S];
    int tid = threadIdx.x;
    int x0 = blockIdx.x * 8, y0 = blockIdx.y * 8;
    {   // stage tb window: 16x16 px, zero pad outside image
        int r = tid >> 4, cL = tid & 15;
        int gy = y0 + r - 4, gx = x0 + cL - 4;
        v8s z = {0,0,0,0,0,0,0,0};
        if (gy >= 0 && gy < H && gx >= 0 && gx < W) {
            const v8s* src = (const v8s*)&tb[(gy * W + gx) * 24];
            *(v8s*)&tbt[tid * TBS]      = src[0];
            *(v8s*)&tbt[tid * TBS + 8]  = src[1];
            *(v8s*)&tbt[tid * TBS + 16] = src[2];
        } else {
            *(v8s*)&tbt[tid * TBS]      = z;
            *(v8s*)&tbt[tid * TBS + 8]  = z;
            *(v8s*)&tbt[tid * TBS + 16] = z;
        }
        if (tid < 48) *(v8s*)&tbt[256 * TBS + tid * 8] = z;   // 16 pad px
    }
    TblCtx ctx = make_tctx(mean);
    __syncthreads();

    // convT2 MFMA (mode-1 A-frags): wave w owns tiles {w, w+4, w+8} -> (3,2,2,2)
    int lane = tid & 63, wv_ = tid >> 6;
    int p = lane & 15, q = lane >> 4;
    const v8s* ap = abuf + 2432;
    int base[3], frow[3], fcol[3];
    bool valid[3];
    #pragma unroll
    for (int g = 0; g < 3; ++g) {
        int tIdx = wv_ + 4 * g;
        valid[g] = (tIdx <= 8);
        int tc = valid[g] ? tIdx : 8;
        int f = tc * 16 + p;                 // flat t3 px < 144
        int r_ = (f * 5462) >> 16;           // f / 12
        frow[g] = r_; fcol[g] = f - r_ * 12;
        base[g] = (r_ * 16 + fcol[g]) * TBS;
    }
    v4f acc0[3], acc1[3];
    #pragma unroll
    for (int g = 0; g < 3; ++g) { acc0[g] = (v4f){0.f,0.f,0.f,0.f}; acc1[g] = (v4f){0.f,0.f,0.f,0.f}; }
    #pragma unroll
    for (int s = 0; s < KSTEPS; ++s) {
        int t, c0, u, v;
        kidx(s, q, t, c0, u, v);
        int off = (u * 16 + v) * TBS + c0;   // shared across the 3 tiles
        v8s af0 = ap[s * 64 + lane];
        v8s af1 = ap[1216 + s * 64 + lane];
        #pragma unroll
        for (int g = 0; g < 3; ++g) {
            v8s b = *(const v8s*)&tbt[base[g] + off];
            acc0[g] = __builtin_amdgcn_mfma_f32_16x16x32_bf16(af0, b, acc0[g], 0, 0, 0);
            acc1[g] = __builtin_amdgcn_mfma_f32_16x16x32_bf16(af1, b, acc1[g], 0, 0, 0);
        }
    }
    // rbf_der via TD -> t3 (zero outside image)
    #pragma unroll
    for (int g = 0; g < 3; ++g) {
        if (valid[g]) {
            int f = (wv_ + 4 * g) * 16 + p;
            int gy = y0 + frow[g] - 2, gx = x0 + fcol[g] - 2;
            bool inimg = (gy >= 0 && gy < H && gx >= 0 && gx < W);
            #pragma unroll
            for (int j = 0; j < 4; ++j)
                t3[f * T3S + q * 4 + j] =
                    inimg ? tbl_eval(TDg, q * 4 + j, acc0[g][j], ctx) : 0.f;
            if (q < 2) {
                #pragma unroll
                for (int j = 0; j < 4; ++j)
                    t3[f * T3S + 16 + q * 4 + j] =
                        inimg ? tbl_eval(TDg, 16 + q * 4 + j, acc1[g][j], ctx) : 0.f;
            }
        }
    }
    __syncthreads();   // tbt fully consumed; reuse as reduction buffer

    // convT1 (24->1, pre-flipped f0t) + final; 4-way channel split across waves
    float* red = (float*)tbt;
    int gq = __builtin_amdgcn_readfirstlane(tid >> 6);
    int px = tid & 63, pr = px >> 3, pc = px & 7;
    float a = 0.f;
    #pragma unroll 1
    for (int cp = 0; cp < 3; ++cp) {
        int c = gq * 6 + cp * 2;               // even -> 8B-aligned float2
        const float* fb0 = f0t + c * 25;
        const float* fb1 = f0t + (c + 1) * 25;
        #pragma unroll
        for (int u = 0; u < 5; ++u)
            #pragma unroll
            for (int v = 0; v < 5; ++v) {
                float2 tp = *(const float2*)&t3[((pr + u) * 12 + (pc + v)) * T3S + c];
                a = fmaf(tp.x, fb0[u * 5 + v], a);
                a = fmaf(tp.y, fb1[u * 5 + v], a);
            }
    }
    red[tid] = a;
    __syncthreads();
    if (tid < 64) {
        float tot = red[tid] + red[64 + tid] + red[128 + tid] + red[192 + tid];
        int pix = (y0 + pr) * W + (x0 + pc);
        float elam = __expf(lamp[0]);
        float xv = x[pix], yv = y[pix];
        out[pix] = xv - (tot + elam * (xv - yv));
    }
}

extern "C" void kernel_launch(void* const* d_in, const int* in_sizes, int n_in,
                              void* d_out, int out_size, void* d_ws, size_t ws_size,
                              hipStream_t stream) {
    const float* x    = (const float*)d_in[0];
    const float* y    = (const float*)d_in[1];
    const float* f0   = (const float*)d_in[3];
    const float* f1   = (const float*)d_in[4];
    const float* aw0  = (const float*)d_in[5];
    const float* aw1  = (const float*)d_in[6];
    const float* mean = (const float*)d_in[7];
    const float* lamp = (const float*)d_in[8];
    float* out = (float*)d_out;

    float* w   = (float*)d_ws;
    float* f0n = w;                          // 600
    float* f0t = w + 640;                    // 600
    v8s*  abuf = (v8s*)(w + 1536);           // 4864*16B -> ends at w+20992
    unsigned* tg = (unsigned*)(w + 27136);   // 3*6168 dwords
    unsigned* T0g = tg;
    unsigned* T1g = tg + TBLN;
    unsigned* TDg = tg + 2 * TBLN;
    short* tb  = (short*)(w + 46080);        // 1.57M shorts

    k_prep<<<75, 256, 0, stream>>>(f0, f1, mean, aw0, aw1, f0n, f0t, abuf, tg);
    dim3 grid(W / 8, H / 8);                 // 32 x 32 = 1024 blocks
    k_fuseA<<<grid, 256, 0, stream>>>(x, f0n, abuf, mean, T0g, T1g, tb);
    k_fuseB<<<grid, 256, 0, stream>>>(tb, abuf, f0t, mean, TDg, x, y, lamp, out);
}

// Round 20
// 45.919 us; speedup vs baseline: 1.2878x; 1.1674x over previous
//
#include <hip/hip_runtime.h>
#include <math.h>

#define H 256
#define W 256
#define HW (H * W)
#define CH 24
#define NK 63
#define T1S 24          // t1 per-pixel stride in shorts (12 dwords, 2-way floor)
#define TBS 24          // tbt per-pixel stride in shorts
#define XPS 40          // xpatch per-pixel stride in shorts (20 dwords, 2-way floor)
#define KSTEPS 19       // K = 600 packed (tap*24 + c), padded to 608
#define NE 257          // table dwords per channel (pairs of 258 samples)
#define TBLN (CH * NE)  // 6168 dwords per table
#define T3S 26          // t3 per-pixel stride in floats

typedef short v8s __attribute__((ext_vector_type(8)));
typedef short v4s __attribute__((ext_vector_type(4)));
typedef float v4f __attribute__((ext_vector_type(4)));

// ---------------- bf16 helper ----------------------------------------------------
__device__ __forceinline__ short f2bf(float v) {
    unsigned u = __float_as_uint(v);
    u += 0x7fff + ((u >> 16) & 1);
    return (short)(u >> 16);
}

// ---------------- table lookup (global, L1-resident) ------------------------------
struct TblCtx { float off, invh; };
__device__ __forceinline__ TblCtx make_tctx(const float* __restrict__ mean) {
    TblCtx c;
    float lo = mean[0] - 12.f;
    float hi = mean[NK - 1] + 12.f;
    c.invh = 257.f / (hi - lo);
    c.off  = -lo * c.invh;
    return c;
}
__device__ __forceinline__ float tbl_eval(const unsigned* __restrict__ tbl, int ch,
                                          float v, const TblCtx& c) {
    float t = fmaf(v, c.invh, c.off);
    t = fminf(fmaxf(t, 0.f), 256.999f);
    float fi = floorf(t);
    float fr = t - fi;
    unsigned u = tbl[ch * NE + (int)fi];        // global dword, L1-hit
    float a = __uint_as_float(u << 16);
    float b = __uint_as_float(u & 0xffff0000u);
    return fmaf(fr, b - a, a);
}

// ---------------- packed-K index helper: k = tap*24 + c, K 600->608 ----------------
__device__ __forceinline__ void kidx(int s, int q, int& t, int& c0, int& u, int& v) {
    int k0 = 32 * s + (q << 3);
    t  = (k0 * 2731) >> 16;        // k0/24
    c0 = k0 - t * 24;
    u  = (t * 3277) >> 14;         // t/5
    v  = t - u * 5;
}

// ---------------- prep: norms, f0n/f0t, A-frag packs, RBF tables -------------------
// abuf: modes 0/1 (conv2/convT2): [mode][mtile 2][kstep 19][lane 64] = 4864 v8s.
//       mode 2 (conv1, K=32 single step): [mtile 2][lane 64] at 4864..4991.
// tables: tg[tt][ch][NE], tt: 0=rbf(aw0), 1=rbf(aw1), 2=rbf_der(aw0); exact 63-tap.
__global__ void k_prep(const float* __restrict__ f0, const float* __restrict__ f1,
                       const float* __restrict__ mean, const float* __restrict__ aw0,
                       const float* __restrict__ aw1,
                       float* __restrict__ f0n, float* __restrict__ f0t,
                       v8s* __restrict__ abuf, unsigned* __restrict__ tg) {
    __shared__ float red[256];
    int tid = threadIdx.x;
    float s1 = 0.f;
    for (int i = tid; i < 14400; i += 256) s1 += f1[i] * f1[i];
    red[tid] = s1; __syncthreads();
    for (int off = 128; off; off >>= 1) { if (tid < off) red[tid] += red[tid + off]; __syncthreads(); }
    float inv1 = 1.f / sqrtf(red[0]);
    __syncthreads();
    // f0 norm in ALL blocks (mode-2 pack needs it in block 19)
    float s0 = 0.f;
    for (int i = tid; i < 600; i += 256) s0 += f0[i] * f0[i];
    red[tid] = s0; __syncthreads();
    for (int off = 128; off; off >>= 1) { if (tid < off) red[tid] += red[tid + off]; __syncthreads(); }
    float inv0 = 1.f / sqrtf(red[0]);
    if (blockIdx.x == 0) {
        for (int i = tid; i < 600; i += 256) {
            int c = i / 25, k = i % 25;
            f0n[i] = f0[i] * inv0;
            f0t[i] = f0[c * 25 + (24 - k)] * inv0;
        }
    }
    int gid = blockIdx.x * 256 + tid;      // 75 blocks -> 19200 threads
    if (gid < 4864) {                      // modes 0/1 A-pack (19 steps, packed K)
        int lane = gid & 63;
        int rest = gid >> 6;               // 0..75
        int s = rest % KSTEPS;
        int md = rest / KSTEPS;            // 0..3
        int mode = md >> 1, m = md & 1;
        int o = m * 16 + (lane & 15);
        v8s av;
        #pragma unroll
        for (int j = 0; j < 8; ++j) {
            int k = 32 * s + 8 * (lane >> 4) + j;
            float wv = 0.f;
            if (o < CH && k < 600) {
                int t = k / 24, c = k - (k / 24) * 24;
                wv = (mode == 0) ? f1[(o * CH + c) * 25 + t]
                                 : f1[(c * CH + o) * 25 + (24 - t)];
                wv *= inv1;
            }
            av[j] = f2bf(wv);
        }
        abuf[gid] = av;
    } else if (gid < 4992) {               // mode 2: conv1 A-pack (K=32, tap-major)
        int rest = gid - 4864;
        int m = rest >> 6, lane = rest & 63;
        int o = m * 16 + (lane & 15);
        v8s av;
        #pragma unroll
        for (int j = 0; j < 8; ++j) {
            int k = 8 * (lane >> 4) + j;   // tap index
            float wv = (o < CH && k < 25) ? f0[o * 25 + k] * inv0 : 0.f;
            av[j] = f2bf(wv);
        }
        abuf[gid] = av;
    }
    // RBF tables: 18504 jobs, one per thread; exact 63-tap sums
    float lo = mean[0] - 12.f;
    float hi = mean[NK - 1] + 12.f;
    float h  = (hi - lo) * (1.f / 257.f);
    if (gid < 3 * TBLN) {
        int tt = gid / TBLN;
        int rest = gid - tt * TBLN;
        int ch = rest / NE;
        int i  = rest - ch * NE;
        const float* wr = ((tt == 1) ? aw1 : aw0) + ch * NK;
        float v0 = fmaf(h, (float)i, lo);
        float v1 = v0 + h;
        float s0v = 0.f, s1v = 0.f;
        for (int k = 0; k < NK; ++k) {
            float m = mean[k], wk = wr[k];
            float d0 = v0 - m, d1 = v1 - m;
            float e0 = __expf(d0 * d0 * -0.005f);
            float e1 = __expf(d1 * d1 * -0.005f);
            if (tt == 2) { e0 *= d0 * -0.01f; e1 *= d1 * -0.01f; }
            s0v = fmaf(e0, wk, s0v);
            s1v = fmaf(e1, wk, s1v);
        }
        unsigned pb = ((unsigned)(unsigned short)f2bf(s1v) << 16)
                    | (unsigned)(unsigned short)f2bf(s0v);
        tg[gid] = pb;
    }
}

// ---------------- fused A: conv1 MFMA + rbf0(T0) -> conv2 MFMA + rbf1(T1) ----------
// 8x8 output tile, 1024 blocks, 4 blocks/CU (~20 KB LDS).
__global__ __launch_bounds__(256, 4) void k_fuseA(const float* __restrict__ x,
        const v8s* __restrict__ abuf, const float* __restrict__ mean,
        const unsigned* __restrict__ T0g, const unsigned* __restrict__ T1g,
        short* __restrict__ tb) {
    __shared__ float xs[256];
    __shared__ __align__(16) short xpb[144 * XPS];  // tap-major patches, 11520 B
    __shared__ __align__(16) short t1[152 * T1S];   // 144 real + 8 pad px
    int tid = threadIdx.x;
    int x0 = blockIdx.x * 8, y0 = blockIdx.y * 8;
    {   // stage x window (16x16, clamped = replication pad)
        int r = tid >> 4, cL = tid & 15;
        int gy = min(max(y0 + r - 4, 0), H - 1);
        int gx = min(max(x0 + cL - 4, 0), W - 1);
        xs[tid] = x[gy * W + gx];
    }
    TblCtx ctx = make_tctx(mean);
    if (tid < 24) {   // zero the 8 t1 pad pixels
        v8s z = {0,0,0,0,0,0,0,0};
        *(v8s*)&t1[144 * T1S + tid * 8] = z;
    }
    __syncthreads();

    // build xpatch: one job per t1 pixel (144), 32 taps each (25 real + 7 zero)
    if (tid < 144) {
        int yi = (tid * 5462) >> 16;        // tid / 12
        int xi = tid - yi * 12;
        int sy = min(max(y0 + yi - 2, 0), H - 1);
        int sx = min(max(x0 + xi - 2, 0), W - 1);
        int iy[5], ix[5];
        #pragma unroll
        for (int u = 0; u < 5; ++u) {
            iy[u] = min(max(sy + u - 2, 0), H - 1) - (y0 - 4);
            ix[u] = min(max(sx + u - 2, 0), W - 1) - (x0 - 4);
        }
        short vals[32];
        #pragma unroll
        for (int u = 0; u < 5; ++u)
            #pragma unroll
            for (int v = 0; v < 5; ++v)
                vals[u * 5 + v] = f2bf(xs[iy[u] * 16 + ix[v]]);
        #pragma unroll
        for (int k = 25; k < 32; ++k) vals[k] = 0;
        #pragma unroll
        for (int g = 0; g < 4; ++g)
            *(v8s*)&xpb[tid * XPS + g * 8] = *(v8s*)&vals[g * 8];
    }
    __syncthreads();

    // stage 1: conv1 via MFMA (mode-2 A-frags, K=32 single step) + rbf0 -> t1
    int lane = tid & 63, wv_ = tid >> 6;
    int p = lane & 15, q = lane >> 4;
    {
        v8s a0s = abuf[4864 + lane];
        v8s a1s = abuf[4928 + lane];
        const v4f z4 = {0.f, 0.f, 0.f, 0.f};
        #pragma unroll
        for (int g = 0; g < 3; ++g) {
            int nt = wv_ + 4 * g;           // ntiles (3,2,2,2) across waves
            if (nt <= 8) {
                int px = nt * 16 + p;
                v8s b = *(const v8s*)&xpb[px * XPS + q * 8];
                v4f c0 = __builtin_amdgcn_mfma_f32_16x16x32_bf16(a0s, b, z4, 0, 0, 0);
                v4f c1 = __builtin_amdgcn_mfma_f32_16x16x32_bf16(a1s, b, z4, 0, 0, 0);
                v4s st;
                #pragma unroll
                for (int j = 0; j < 4; ++j)
                    st[j] = f2bf(tbl_eval(T0g, q * 4 + j, c0[j], ctx));
                *(v4s*)&t1[px * T1S + q * 4] = st;
                if (q < 2) {
                    #pragma unroll
                    for (int j = 0; j < 4; ++j)
                        st[j] = f2bf(tbl_eval(T0g, 16 + q * 4 + j, c1[j], ctx));
                    *(v4s*)&t1[px * T1S + 16 + q * 4] = st;
                }
            }
        }
    }
    __syncthreads();

    // stage 2: conv2 MFMA; wave = one 16-px N-tile (2 rows of 8); K packed 608
    int row = (wv_ * 16 + p) >> 3, col = p & 7;
    int pxbase = row * 12 + col;
    v4f a0v = {0.f,0.f,0.f,0.f}, a1v = {0.f,0.f,0.f,0.f};
    #pragma unroll
    for (int s = 0; s < KSTEPS; ++s) {
        int t, c0, u, v;
        kidx(s, q, t, c0, u, v);
        v8s b   = *(const v8s*)&t1[(pxbase + u * 12 + v) * T1S + c0];
        v8s af0 = abuf[s * 64 + lane];
        v8s af1 = abuf[1216 + s * 64 + lane];
        a0v = __builtin_amdgcn_mfma_f32_16x16x32_bf16(af0, b, a0v, 0, 0, 0);
        a1v = __builtin_amdgcn_mfma_f32_16x16x32_bf16(af1, b, a1v, 0, 0, 0);
    }
    // epilogue: rbf1 via T1 -> tb[pix][ch] (channel-minor), 8B stores
    int pix = (y0 + row) * W + (x0 + col);
    v4s st;
    #pragma unroll
    for (int j = 0; j < 4; ++j)
        st[j] = f2bf(tbl_eval(T1g, q * 4 + j, a0v[j], ctx));
    *(v4s*)&tb[pix * 24 + q * 4] = st;
    if (q < 2) {
        #pragma unroll
        for (int j = 0; j < 4; ++j)
            st[j] = f2bf(tbl_eval(T1g, 16 + q * 4 + j, a1v[j], ctx));
        *(v4s*)&tb[pix * 24 + 16 + q * 4] = st;
    }
}

// ---------------- fused B: convT2 MFMA + rbf'(TD) -> convT1 + final ----------------
// (unchanged from R19 champion)
__global__ __launch_bounds__(256, 4) void k_fuseB(const short* __restrict__ tb,
        const v8s* __restrict__ abuf, const float* __restrict__ f0t,
        const float* __restrict__ mean, const unsigned* __restrict__ TDg,
        const float* __restrict__ x, const float* __restrict__ y,
        const float* __restrict__ lamp, float* __restrict__ out) {
    __shared__ __align__(16) short tbt[272 * TBS];  // 256 real + 16 pad px; red[] in ph4
    __shared__ float t3[144 * T3S];
    int tid = threadIdx.x;
    int x0 = blockIdx.x * 8, y0 = blockIdx.y * 8;
    {   // stage tb window: 16x16 px, zero pad outside image
        int r = tid >> 4, cL = tid & 15;
        int gy = y0 + r - 4, gx = x0 + cL - 4;
        v8s z = {0,0,0,0,0,0,0,0};
        if (gy >= 0 && gy < H && gx >= 0 && gx < W) {
            const v8s* src = (const v8s*)&tb[(gy * W + gx) * 24];
            *(v8s*)&tbt[tid * TBS]      = src[0];
            *(v8s*)&tbt[tid * TBS + 8]  = src[1];
            *(v8s*)&tbt[tid * TBS + 16] = src[2];
        } else {
            *(v8s*)&tbt[tid * TBS]      = z;
            *(v8s*)&tbt[tid * TBS + 8]  = z;
            *(v8s*)&tbt[tid * TBS + 16] = z;
        }
        if (tid < 48) *(v8s*)&tbt[256 * TBS + tid * 8] = z;   // 16 pad px
    }
    TblCtx ctx = make_tctx(mean);
    __syncthreads();

    // convT2 MFMA (mode-1 A-frags): wave w owns tiles {w, w+4, w+8} -> (3,2,2,2)
    int lane = tid & 63, wv_ = tid >> 6;
    int p = lane & 15, q = lane >> 4;
    const v8s* ap = abuf + 2432;
    int base[3], frow[3], fcol[3];
    bool valid[3];
    #pragma unroll
    for (int g = 0; g < 3; ++g) {
        int tIdx = wv_ + 4 * g;
        valid[g] = (tIdx <= 8);
        int tc = valid[g] ? tIdx : 8;
        int f = tc * 16 + p;                 // flat t3 px < 144
        int r_ = (f * 5462) >> 16;           // f / 12
        frow[g] = r_; fcol[g] = f - r_ * 12;
        base[g] = (r_ * 16 + fcol[g]) * TBS;
    }
    v4f acc0[3], acc1[3];
    #pragma unroll
    for (int g = 0; g < 3; ++g) { acc0[g] = (v4f){0.f,0.f,0.f,0.f}; acc1[g] = (v4f){0.f,0.f,0.f,0.f}; }
    #pragma unroll
    for (int s = 0; s < KSTEPS; ++s) {
        int t, c0, u, v;
        kidx(s, q, t, c0, u, v);
        int off = (u * 16 + v) * TBS + c0;   // shared across the 3 tiles
        v8s af0 = ap[s * 64 + lane];
        v8s af1 = ap[1216 + s * 64 + lane];
        #pragma unroll
        for (int g = 0; g < 3; ++g) {
            v8s b = *(const v8s*)&tbt[base[g] + off];
            acc0[g] = __builtin_amdgcn_mfma_f32_16x16x32_bf16(af0, b, acc0[g], 0, 0, 0);
            acc1[g] = __builtin_amdgcn_mfma_f32_16x16x32_bf16(af1, b, acc1[g], 0, 0, 0);
        }
    }
    // rbf_der via TD -> t3 (zero outside image)
    #pragma unroll
    for (int g = 0; g < 3; ++g) {
        if (valid[g]) {
            int f = (wv_ + 4 * g) * 16 + p;
            int gy = y0 + frow[g] - 2, gx = x0 + fcol[g] - 2;
            bool inimg = (gy >= 0 && gy < H && gx >= 0 && gx < W);
            #pragma unroll
            for (int j = 0; j < 4; ++j)
                t3[f * T3S + q * 4 + j] =
                    inimg ? tbl_eval(TDg, q * 4 + j, acc0[g][j], ctx) : 0.f;
            if (q < 2) {
                #pragma unroll
                for (int j = 0; j < 4; ++j)
                    t3[f * T3S + 16 + q * 4 + j] =
                        inimg ? tbl_eval(TDg, 16 + q * 4 + j, acc1[g][j], ctx) : 0.f;
            }
        }
    }
    __syncthreads();   // tbt fully consumed; reuse as reduction buffer

    // convT1 (24->1, pre-flipped f0t) + final; 4-way channel split across waves
    float* red = (float*)tbt;
    int gq = __builtin_amdgcn_readfirstlane(tid >> 6);
    int px = tid & 63, pr = px >> 3, pc = px & 7;
    float a = 0.f;
    #pragma unroll 1
    for (int cp = 0; cp < 3; ++cp) {
        int c = gq * 6 + cp * 2;               // even -> 8B-aligned float2
        const float* fb0 = f0t + c * 25;
        const float* fb1 = f0t + (c + 1) * 25;
        #pragma unroll
        for (int u = 0; u < 5; ++u)
            #pragma unroll
            for (int v = 0; v < 5; ++v) {
                float2 tp = *(const float2*)&t3[((pr + u) * 12 + (pc + v)) * T3S + c];
                a = fmaf(tp.x, fb0[u * 5 + v], a);
                a = fmaf(tp.y, fb1[u * 5 + v], a);
            }
    }
    red[tid] = a;
    __syncthreads();
    if (tid < 64) {
        float tot = red[tid] + red[64 + tid] + red[128 + tid] + red[192 + tid];
        int pix = (y0 + pr) * W + (x0 + pc);
        float elam = __expf(lamp[0]);
        float xv = x[pix], yv = y[pix];
        out[pix] = xv - (tot + elam * (xv - yv));
    }
}

extern "C" void kernel_launch(void* const* d_in, const int* in_sizes, int n_in,
                              void* d_out, int out_size, void* d_ws, size_t ws_size,
                              hipStream_t stream) {
    const float* x    = (const float*)d_in[0];
    const float* y    = (const float*)d_in[1];
    const float* f0   = (const float*)d_in[3];
    const float* f1   = (const float*)d_in[4];
    const float* aw0  = (const float*)d_in[5];
    const float* aw1  = (const float*)d_in[6];
    const float* mean = (const float*)d_in[7];
    const float* lamp = (const float*)d_in[8];
    float* out = (float*)d_out;

    float* w   = (float*)d_ws;
    float* f0n = w;                          // 600
    float* f0t = w + 640;                    // 600
    v8s*  abuf = (v8s*)(w + 1536);           // 4992*16B -> ends at w+21504
    unsigned* tg = (unsigned*)(w + 27136);   // 3*6168 dwords
    unsigned* T0g = tg;
    unsigned* T1g = tg + TBLN;
    unsigned* TDg = tg + 2 * TBLN;
    short* tb  = (short*)(w + 46080);        // 1.57M shorts

    k_prep<<<75, 256, 0, stream>>>(f0, f1, mean, aw0, aw1, f0n, f0t, abuf, tg);
    dim3 grid(W / 8, H / 8);                 // 32 x 32 = 1024 blocks
    k_fuseA<<<grid, 256, 0, stream>>>(x, abuf, mean, T0g, T1g, tb);
    k_fuseB<<<grid, 256, 0, stream>>>(tb, abuf, f0t, mean, TDg, x, y, lamp, out);
}

// Round 21
// 45.044 us; speedup vs baseline: 1.3128x; 1.0194x over previous
//
#include <hip/hip_runtime.h>
#include <math.h>

#define H 256
#define W 256
#define HW (H * W)
#define CH 24
#define NK 63
#define T1S 24          // t1 per-pixel stride in shorts (12 dwords, 2-way floor)
#define TBS 24          // tbt per-pixel stride in shorts
#define XPS 40          // xpatch per-pixel stride in shorts (20 dwords, 2-way floor)
#define KSTEPS 19       // K = 600 packed (tap*24 + c), padded to 608
#define NE 257          // table dwords per channel (pairs of 258 samples)
#define TBLN (CH * NE)  // 6168 dwords per table

typedef short v8s __attribute__((ext_vector_type(8)));
typedef short v4s __attribute__((ext_vector_type(4)));
typedef float v4f __attribute__((ext_vector_type(4)));

// ---------------- bf16 helper ----------------------------------------------------
__device__ __forceinline__ short f2bf(float v) {
    unsigned u = __float_as_uint(v);
    u += 0x7fff + ((u >> 16) & 1);
    return (short)(u >> 16);
}

// ---------------- table lookup (global, L1-resident) ------------------------------
struct TblCtx { float off, invh; };
__device__ __forceinline__ TblCtx make_tctx(const float* __restrict__ mean) {
    TblCtx c;
    float lo = mean[0] - 12.f;
    float hi = mean[NK - 1] + 12.f;
    c.invh = 257.f / (hi - lo);
    c.off  = -lo * c.invh;
    return c;
}
__device__ __forceinline__ float tbl_eval(const unsigned* __restrict__ tbl, int ch,
                                          float v, const TblCtx& c) {
    float t = fmaf(v, c.invh, c.off);
    t = fminf(fmaxf(t, 0.f), 256.999f);
    float fi = floorf(t);
    float fr = t - fi;
    unsigned u = tbl[ch * NE + (int)fi];        // global dword, L1-hit
    float a = __uint_as_float(u << 16);
    float b = __uint_as_float(u & 0xffff0000u);
    return fmaf(fr, b - a, a);
}

// ---------------- packed-K index helper: k = tap*24 + c, K 600->608 ----------------
__device__ __forceinline__ void kidx(int s, int q, int& t, int& c0, int& u, int& v) {
    int k0 = 32 * s + (q << 3);
    t  = (k0 * 2731) >> 16;        // k0/24
    c0 = k0 - t * 24;
    u  = (t * 3277) >> 14;         // t/5
    v  = t - u * 5;
}

// ---------------- prep: norms, A-frag packs (modes 0-3), RBF tables ----------------
// abuf: modes 0/1 (conv2/convT2): [mode][mtile 2][kstep 19][lane 64] = 4864 v8s.
//       mode 2 (conv1, K=32):   4864..4991 ([mtile 2][lane 64]).
//       mode 3 (convT1, K=608): 4992..6207 ([kstep 19][lane 64], row 0 only).
// tables: tg[tt][ch][NE], tt: 0=rbf(aw0), 1=rbf(aw1), 2=rbf_der(aw0); exact 63-tap.
__global__ void k_prep(const float* __restrict__ f0, const float* __restrict__ f1,
                       const float* __restrict__ mean, const float* __restrict__ aw0,
                       const float* __restrict__ aw1,
                       v8s* __restrict__ abuf, unsigned* __restrict__ tg) {
    __shared__ float red[256];
    int tid = threadIdx.x;
    float s1 = 0.f;
    for (int i = tid; i < 14400; i += 256) s1 += f1[i] * f1[i];
    red[tid] = s1; __syncthreads();
    for (int off = 128; off; off >>= 1) { if (tid < off) red[tid] += red[tid + off]; __syncthreads(); }
    float inv1 = 1.f / sqrtf(red[0]);
    __syncthreads();
    float s0 = 0.f;
    for (int i = tid; i < 600; i += 256) s0 += f0[i] * f0[i];
    red[tid] = s0; __syncthreads();
    for (int off = 128; off; off >>= 1) { if (tid < off) red[tid] += red[tid + off]; __syncthreads(); }
    float inv0 = 1.f / sqrtf(red[0]);

    int gid = blockIdx.x * 256 + tid;      // 75 blocks -> 19200 threads
    if (gid < 4864) {                      // modes 0/1 A-pack (19 steps, packed K)
        int lane = gid & 63;
        int rest = gid >> 6;               // 0..75
        int s = rest % KSTEPS;
        int md = rest / KSTEPS;            // 0..3
        int mode = md >> 1, m = md & 1;
        int o = m * 16 + (lane & 15);
        v8s av;
        #pragma unroll
        for (int j = 0; j < 8; ++j) {
            int k = 32 * s + 8 * (lane >> 4) + j;
            float wv = 0.f;
            if (o < CH && k < 600) {
                int t = k / 24, c = k - (k / 24) * 24;
                wv = (mode == 0) ? f1[(o * CH + c) * 25 + t]
                                 : f1[(c * CH + o) * 25 + (24 - t)];
                wv *= inv1;
            }
            av[j] = f2bf(wv);
        }
        abuf[gid] = av;
    } else if (gid < 4992) {               // mode 2: conv1 A-pack (K=32, tap-major)
        int rest = gid - 4864;
        int m = rest >> 6, lane = rest & 63;
        int o = m * 16 + (lane & 15);
        v8s av;
        #pragma unroll
        for (int j = 0; j < 8; ++j) {
            int k = 8 * (lane >> 4) + j;   // tap index
            float wv = (o < CH && k < 25) ? f0[o * 25 + k] * inv0 : 0.f;
            av[j] = f2bf(wv);
        }
        abuf[gid] = av;
    } else if (gid < 6208) {               // mode 3: convT1 A-pack (row 0 only)
        int rest = gid - 4992;
        int s = rest >> 6, lane = rest & 63;
        int o = lane & 15;
        v8s av;
        #pragma unroll
        for (int j = 0; j < 8; ++j) {
            int k = 32 * s + 8 * (lane >> 4) + j;
            float wv = 0.f;
            if (o == 0 && k < 600) {
                int t = k / 24, c = k - (k / 24) * 24;
                wv = f0[c * 25 + (24 - t)] * inv0;   // pre-flipped convT1 weight
            }
            av[j] = f2bf(wv);
        }
        abuf[gid] = av;
    }
    // RBF tables: 18504 jobs, one per thread; exact 63-tap sums
    float lo = mean[0] - 12.f;
    float hi = mean[NK - 1] + 12.f;
    float h  = (hi - lo) * (1.f / 257.f);
    if (gid < 3 * TBLN) {
        int tt = gid / TBLN;
        int rest = gid - tt * TBLN;
        int ch = rest / NE;
        int i  = rest - ch * NE;
        const float* wr = ((tt == 1) ? aw1 : aw0) + ch * NK;
        float v0 = fmaf(h, (float)i, lo);
        float v1 = v0 + h;
        float s0v = 0.f, s1v = 0.f;
        for (int k = 0; k < NK; ++k) {
            float m = mean[k], wk = wr[k];
            float d0 = v0 - m, d1 = v1 - m;
            float e0 = __expf(d0 * d0 * -0.005f);
            float e1 = __expf(d1 * d1 * -0.005f);
            if (tt == 2) { e0 *= d0 * -0.01f; e1 *= d1 * -0.01f; }
            s0v = fmaf(e0, wk, s0v);
            s1v = fmaf(e1, wk, s1v);
        }
        unsigned pb = ((unsigned)(unsigned short)f2bf(s1v) << 16)
                    | (unsigned)(unsigned short)f2bf(s0v);
        tg[gid] = pb;
    }
}

// ---------------- fused A: conv1 MFMA + rbf0(T0) -> conv2 MFMA + rbf1(T1) ----------
// (unchanged from R20 champion)
__global__ __launch_bounds__(256, 4) void k_fuseA(const float* __restrict__ x,
        const v8s* __restrict__ abuf, const float* __restrict__ mean,
        const unsigned* __restrict__ T0g, const unsigned* __restrict__ T1g,
        short* __restrict__ tb) {
    __shared__ float xs[256];
    __shared__ __align__(16) short xpb[144 * XPS];  // tap-major patches
    __shared__ __align__(16) short t1[152 * T1S];   // 144 real + 8 pad px
    int tid = threadIdx.x;
    int x0 = blockIdx.x * 8, y0 = blockIdx.y * 8;
    {
        int r = tid >> 4, cL = tid & 15;
        int gy = min(max(y0 + r - 4, 0), H - 1);
        int gx = min(max(x0 + cL - 4, 0), W - 1);
        xs[tid] = x[gy * W + gx];
    }
    TblCtx ctx = make_tctx(mean);
    if (tid < 24) {
        v8s z = {0,0,0,0,0,0,0,0};
        *(v8s*)&t1[144 * T1S + tid * 8] = z;
    }
    __syncthreads();

    if (tid < 144) {
        int yi = (tid * 5462) >> 16;        // tid / 12
        int xi = tid - yi * 12;
        int sy = min(max(y0 + yi - 2, 0), H - 1);
        int sx = min(max(x0 + xi - 2, 0), W - 1);
        int iy[5], ix[5];
        #pragma unroll
        for (int u = 0; u < 5; ++u) {
            iy[u] = min(max(sy + u - 2, 0), H - 1) - (y0 - 4);
            ix[u] = min(max(sx + u - 2, 0), W - 1) - (x0 - 4);
        }
        short vals[32];
        #pragma unroll
        for (int u = 0; u < 5; ++u)
            #pragma unroll
            for (int v = 0; v < 5; ++v)
                vals[u * 5 + v] = f2bf(xs[iy[u] * 16 + ix[v]]);
        #pragma unroll
        for (int k = 25; k < 32; ++k) vals[k] = 0;
        #pragma unroll
        for (int g = 0; g < 4; ++g)
            *(v8s*)&xpb[tid * XPS + g * 8] = *(v8s*)&vals[g * 8];
    }
    __syncthreads();

    int lane = tid & 63, wv_ = tid >> 6;
    int p = lane & 15, q = lane >> 4;
    {
        v8s a0s = abuf[4864 + lane];
        v8s a1s = abuf[4928 + lane];
        const v4f z4 = {0.f, 0.f, 0.f, 0.f};
        #pragma unroll
        for (int g = 0; g < 3; ++g) {
            int nt = wv_ + 4 * g;
            if (nt <= 8) {
                int px = nt * 16 + p;
                v8s b = *(const v8s*)&xpb[px * XPS + q * 8];
                v4f c0 = __builtin_amdgcn_mfma_f32_16x16x32_bf16(a0s, b, z4, 0, 0, 0);
                v4f c1 = __builtin_amdgcn_mfma_f32_16x16x32_bf16(a1s, b, z4, 0, 0, 0);
                v4s st;
                #pragma unroll
                for (int j = 0; j < 4; ++j)
                    st[j] = f2bf(tbl_eval(T0g, q * 4 + j, c0[j], ctx));
                *(v4s*)&t1[px * T1S + q * 4] = st;
                if (q < 2) {
                    #pragma unroll
                    for (int j = 0; j < 4; ++j)
                        st[j] = f2bf(tbl_eval(T0g, 16 + q * 4 + j, c1[j], ctx));
                    *(v4s*)&t1[px * T1S + 16 + q * 4] = st;
                }
            }
        }
    }
    __syncthreads();

    int row = (wv_ * 16 + p) >> 3, col = p & 7;
    int pxbase = row * 12 + col;
    v4f a0v = {0.f,0.f,0.f,0.f}, a1v = {0.f,0.f,0.f,0.f};
    #pragma unroll
    for (int s = 0; s < KSTEPS; ++s) {
        int t, c0, u, v;
        kidx(s, q, t, c0, u, v);
        v8s b   = *(const v8s*)&t1[(pxbase + u * 12 + v) * T1S + c0];
        v8s af0 = abuf[s * 64 + lane];
        v8s af1 = abuf[1216 + s * 64 + lane];
        a0v = __builtin_amdgcn_mfma_f32_16x16x32_bf16(af0, b, a0v, 0, 0, 0);
        a1v = __builtin_amdgcn_mfma_f32_16x16x32_bf16(af1, b, a1v, 0, 0, 0);
    }
    int pix = (y0 + row) * W + (x0 + col);
    v4s st;
    #pragma unroll
    for (int j = 0; j < 4; ++j)
        st[j] = f2bf(tbl_eval(T1g, q * 4 + j, a0v[j], ctx));
    *(v4s*)&tb[pix * 24 + q * 4] = st;
    if (q < 2) {
        #pragma unroll
        for (int j = 0; j < 4; ++j)
            st[j] = f2bf(tbl_eval(T1g, 16 + q * 4 + j, a1v[j], ctx));
        *(v4s*)&tb[pix * 24 + 16 + q * 4] = st;
    }
}

// ---------------- fused B: convT2 MFMA + rbf'(TD) -> convT1 MFMA + final -----------
// 8x8 output tile, 1024 blocks, 4 blocks/CU (~21 KB LDS).
// t3 now bf16 stride 24; convT1 = 19 MFMA/wave (mode-3 A, row 0 = output).
__global__ __launch_bounds__(256, 4) void k_fuseB(const short* __restrict__ tb,
        const v8s* __restrict__ abuf, const float* __restrict__ mean,
        const unsigned* __restrict__ TDg, const float* __restrict__ x,
        const float* __restrict__ y, const float* __restrict__ lamp,
        float* __restrict__ out) {
    __shared__ __align__(16) short tbt[272 * TBS];  // 256 real + 16 pad px
    __shared__ __align__(16) short t3b[152 * T1S];  // 144 real + 8 pad px, bf16
    int tid = threadIdx.x;
    int x0 = blockIdx.x * 8, y0 = blockIdx.y * 8;
    {   // stage tb window: 16x16 px, zero pad outside image
        int r = tid >> 4, cL = tid & 15;
        int gy = y0 + r - 4, gx = x0 + cL - 4;
        v8s z = {0,0,0,0,0,0,0,0};
        if (gy >= 0 && gy < H && gx >= 0 && gx < W) {
            const v8s* src = (const v8s*)&tb[(gy * W + gx) * 24];
            *(v8s*)&tbt[tid * TBS]      = src[0];
            *(v8s*)&tbt[tid * TBS + 8]  = src[1];
            *(v8s*)&tbt[tid * TBS + 16] = src[2];
        } else {
            *(v8s*)&tbt[tid * TBS]      = z;
            *(v8s*)&tbt[tid * TBS + 8]  = z;
            *(v8s*)&tbt[tid * TBS + 16] = z;
        }
        if (tid < 48) *(v8s*)&tbt[256 * TBS + tid * 8] = z;   // tbt pad px
        if (tid < 24) *(v8s*)&t3b[144 * T1S + tid * 8] = z;   // t3b pad px
    }
    TblCtx ctx = make_tctx(mean);
    __syncthreads();

    // phase 3: convT2 MFMA (mode-1 A): wave w owns tiles {w, w+4, w+8} -> (3,2,2,2)
    int lane = tid & 63, wv_ = tid >> 6;
    int p = lane & 15, q = lane >> 4;
    const v8s* ap = abuf + 2432;
    int base[3], frow[3], fcol[3];
    bool valid[3];
    #pragma unroll
    for (int g = 0; g < 3; ++g) {
        int tIdx = wv_ + 4 * g;
        valid[g] = (tIdx <= 8);
        int tc = valid[g] ? tIdx : 8;
        int f = tc * 16 + p;                 // flat t3 px < 144
        int r_ = (f * 5462) >> 16;           // f / 12
        frow[g] = r_; fcol[g] = f - r_ * 12;
        base[g] = (r_ * 16 + fcol[g]) * TBS;
    }
    v4f acc0[3], acc1[3];
    #pragma unroll
    for (int g = 0; g < 3; ++g) { acc0[g] = (v4f){0.f,0.f,0.f,0.f}; acc1[g] = (v4f){0.f,0.f,0.f,0.f}; }
    #pragma unroll
    for (int s = 0; s < KSTEPS; ++s) {
        int t, c0, u, v;
        kidx(s, q, t, c0, u, v);
        int off = (u * 16 + v) * TBS + c0;
        v8s af0 = ap[s * 64 + lane];
        v8s af1 = ap[1216 + s * 64 + lane];
        #pragma unroll
        for (int g = 0; g < 3; ++g) {
            v8s b = *(const v8s*)&tbt[base[g] + off];
            acc0[g] = __builtin_amdgcn_mfma_f32_16x16x32_bf16(af0, b, acc0[g], 0, 0, 0);
            acc1[g] = __builtin_amdgcn_mfma_f32_16x16x32_bf16(af1, b, acc1[g], 0, 0, 0);
        }
    }
    // rbf_der via TD -> t3b (bf16, zero outside image)
    #pragma unroll
    for (int g = 0; g < 3; ++g) {
        if (valid[g]) {
            int f = (wv_ + 4 * g) * 16 + p;
            int gy = y0 + frow[g] - 2, gx = x0 + fcol[g] - 2;
            bool inimg = (gy >= 0 && gy < H && gx >= 0 && gx < W);
            v4s st;
            #pragma unroll
            for (int j = 0; j < 4; ++j)
                st[j] = inimg ? f2bf(tbl_eval(TDg, q * 4 + j, acc0[g][j], ctx)) : (short)0;
            *(v4s*)&t3b[f * T1S + q * 4] = st;
            if (q < 2) {
                #pragma unroll
                for (int j = 0; j < 4; ++j)
                    st[j] = inimg ? f2bf(tbl_eval(TDg, 16 + q * 4 + j, acc1[g][j], ctx)) : (short)0;
                *(v4s*)&t3b[f * T1S + 16 + q * 4] = st;
            }
        }
    }
    __syncthreads();

    // phase 4: convT1 via MFMA (mode-3 A, row 0) + final combine.
    // wave w owns output N-tile w (16 px of the 8x8 tile); K packed 608.
    {
        int opix = wv_ * 16 + p;
        int pr = opix >> 3, pc = opix & 7;
        int pxbase = pr * 12 + pc;
        const v8s* at = abuf + 4992;
        v4f acc = {0.f, 0.f, 0.f, 0.f};
        #pragma unroll
        for (int s = 0; s < KSTEPS; ++s) {
            int t, c0, u, v;
            kidx(s, q, t, c0, u, v);
            v8s b  = *(const v8s*)&t3b[(pxbase + u * 12 + v) * T1S + c0];
            v8s af = at[s * 64 + lane];
            acc = __builtin_amdgcn_mfma_f32_16x16x32_bf16(af, b, acc, 0, 0, 0);
        }
        if (q == 0) {   // row 0 of C = convT1 output for pixel (pr, pc)
            int pix = (y0 + pr) * W + (x0 + pc);
            float elam = __expf(lamp[0]);
            float xv = x[pix], yv = y[pix];
            out[pix] = xv - (acc[0] + elam * (xv - yv));
        }
    }
}

extern "C" void kernel_launch(void* const* d_in, const int* in_sizes, int n_in,
                              void* d_out, int out_size, void* d_ws, size_t ws_size,
                              hipStream_t stream) {
    const float* x    = (const float*)d_in[0];
    const float* y    = (const float*)d_in[1];
    const float* f0   = (const float*)d_in[3];
    const float* f1   = (const float*)d_in[4];
    const float* aw0  = (const float*)d_in[5];
    const float* aw1  = (const float*)d_in[6];
    const float* mean = (const float*)d_in[7];
    const float* lamp = (const float*)d_in[8];
    float* out = (float*)d_out;

    float* w   = (float*)d_ws;
    v8s*  abuf = (v8s*)(w + 1536);           // 6208*16B -> ends at byte 105472
    unsigned* tg = (unsigned*)(w + 27136);   // 3*6168 dwords (byte 108544+)
    unsigned* T0g = tg;
    unsigned* T1g = tg + TBLN;
    unsigned* TDg = tg + 2 * TBLN;
    short* tb  = (short*)(w + 46080);        // 1.57M shorts

    k_prep<<<75, 256, 0, stream>>>(f0, f1, mean, aw0, aw1, abuf, tg);
    dim3 grid(W / 8, H / 8);                 // 32 x 32 = 1024 blocks
    k_fuseA<<<grid, 256, 0, stream>>>(x, abuf, mean, T0g, T1g, tb);
    k_fuseB<<<grid, 256, 0, stream>>>(tb, abuf, mean, TDg, x, y, lamp, out);
}